// Round 11
// baseline (228.378 us; speedup 1.0000x reference)
//
#include <hip/hip_runtime.h>

#define N_SEQ 8192
#define HDIM  128

typedef _Float16 half8v  __attribute__((ext_vector_type(8)));
typedef float    floatx16 __attribute__((ext_vector_type(16)));
typedef unsigned int uint32;

// ---------------------------------------------------------------------------
// stage_tile: async global->LDS copy of one 32-key tile (K 8KB + V 8KB) into
// a 16KB LDS buffer, 4 chunks/wave. Layouts are lane-major 1KB chunks, so the
// wave-uniform-base + lane*16 LDS write pattern of global_load_lds matches.
// Completion fenced by caller's __syncthreads (vmcnt(0) before s_barrier).
// ---------------------------------------------------------------------------
static __device__ __forceinline__ void stage_tile(
        const _Float16* __restrict__ K16s, const _Float16* __restrict__ Vs,
        _Float16* lds, size_t nt, int wv, int lane) {
    #pragma unroll
    for (int i = 0; i < 4; i++) {
        const int c = wv * 4 + i;
        const _Float16* base = (c < 8) ? (K16s + (nt * 8 + c) * 512)
                                       : (Vs + (nt * 8 + (size_t)(c - 8)) * 512);
        __builtin_amdgcn_global_load_lds(
            (const __attribute__((address_space(1))) void*)(base + lane * 8),
            (__attribute__((address_space(3))) void*)(lds + c * 512),
            16, 0, 0);
    }
}

// ---- PV: oacc += V(tile) . P(tile), P given as packed-f16 C-layout regs ----
static __device__ __forceinline__ void do_pv(const half8v (&vsrc)[8], const uint32 (&hpk)[8],
                                             floatx16 (&oacc)[4], int q5) {
    #pragma unroll
    for (int kc2 = 0; kc2 < 2; kc2++) {
        uint32 pass0 = q5 ? hpk[4 * kc2 + 0] : hpk[4 * kc2 + 2];
        uint32 pass1 = q5 ? hpk[4 * kc2 + 1] : hpk[4 * kc2 + 3];
        uint32 r0 = (uint32)__shfl_xor((int)pass0, 32, 64);
        uint32 r1 = (uint32)__shfl_xor((int)pass1, 32, 64);
        uint32 b0 = q5 ? r0 : hpk[4 * kc2 + 0];
        uint32 b1 = q5 ? r1 : hpk[4 * kc2 + 1];
        uint32 b2 = q5 ? hpk[4 * kc2 + 2] : r0;
        uint32 b3 = q5 ? hpk[4 * kc2 + 3] : r1;
        uint4 bu = make_uint4(b0, b1, b2, b3);
        half8v bfrag = __builtin_bit_cast(half8v, bu);
        #pragma unroll
        for (int dt = 0; dt < 4; dt++)
            oacc[dt] = __builtin_amdgcn_mfma_f32_32x32x16_f16(vsrc[dt * 2 + kc2], bfrag, oacc[dt], 0, 0, 0);
    }
}

// ---- one pipeline step: ds_read(t), rescale-if, PV(t-1), S(t), softmax(t) ----
template <bool DO_PV>
static __device__ __forceinline__ void pipe_step(
        const half8v (&qf)[8], half8v (&vin)[8], const half8v (&vprev)[8],
        floatx16 (&oacc)[4], uint32 (&hpk)[8],
        float& runm, float& lsum, float& palpha, bool& pflag,
        const _Float16* lds, int lane, int q5) {
    half8v kf[8];
    #pragma unroll
    for (int kc = 0; kc < 8; kc++)
        kf[kc] = *(const half8v*)(lds + kc * 512 + lane * 8);
    #pragma unroll
    for (int j = 0; j < 8; j++)
        vin[j] = *(const half8v*)(lds + (8 + j) * 512 + lane * 8);
    if (pflag) {
        #pragma unroll
        for (int dt = 0; dt < 4; dt++)
            #pragma unroll
            for (int r = 0; r < 16; r++) oacc[dt][r] *= palpha;
        pflag = false;
    }
    if (DO_PV) do_pv(vprev, hpk, oacc, q5);
    floatx16 s0, s1;
    #pragma unroll
    for (int r = 0; r < 16; r++) { s0[r] = 0.0f; s1[r] = 0.0f; }
    #pragma unroll
    for (int kc = 0; kc < 4; kc++)
        s0 = __builtin_amdgcn_mfma_f32_32x32x16_f16(kf[kc], qf[kc], s0, 0, 0, 0);
    #pragma unroll
    for (int kc = 4; kc < 8; kc++)
        s1 = __builtin_amdgcn_mfma_f32_32x32x16_f16(kf[kc], qf[kc], s1, 0, 0, 0);
    float sc[16];
    #pragma unroll
    for (int r = 0; r < 16; r++) sc[r] = s0[r] + s1[r];
    float tm[8];
    #pragma unroll
    for (int r = 0; r < 8; r++) tm[r] = fmaxf(sc[r], sc[r + 8]);
    #pragma unroll
    for (int w = 4; w; w >>= 1)
        #pragma unroll
        for (int r = 0; r < w; r++) tm[r] = fmaxf(tm[r], tm[r + w]);
    float cmax = fmaxf(tm[0], __shfl_xor(tm[0], 32, 64));
    if (__any(cmax > runm + 12.0f)) {
        const float mnew = fmaxf(runm, cmax);
        palpha = __builtin_amdgcn_exp2f(runm - mnew);
        runm = mnew;
        lsum *= palpha;
        pflag = true;
    }
    float p[16];
    #pragma unroll
    for (int r = 0; r < 16; r++) p[r] = __builtin_amdgcn_exp2f(sc[r] - runm);
    float ts[8];
    #pragma unroll
    for (int r = 0; r < 8; r++) ts[r] = p[r] + p[r + 8];
    #pragma unroll
    for (int w = 4; w; w >>= 1)
        #pragma unroll
        for (int r = 0; r < w; r++) ts[r] += ts[r + w];
    lsum += ts[0];
    #pragma unroll
    for (int t2 = 0; t2 < 8; t2++) {
        auto pk = __builtin_amdgcn_cvt_pkrtz(p[2 * t2], p[2 * t2 + 1]);
        hpk[t2] = __builtin_bit_cast(uint32, pk);
    }
}

// ---------------------------------------------------------------------------
// fa_all: SINGLE-DISPATCH flash attention. Phases:
//  1) prep: blocks with lid < 256 convert one 32-key K/V tile fp32->f16 into
//     mfma-operand-order buffers (prep_kv body, validated R0-R10).
//  2) grid gate: device-scope counter. Deadlock-free: __launch_bounds__(256,2)
//     + 33.8KB LDS guarantee 2 blocks/CU; grid = S*64 <= 512 = full residency.
//  3) main loop: R8's 2-buffer __syncthreads pipeline (fastest measured,
//     55.8us; R10's counted-vmcnt ring was neutral -> reverted).
//  4) epilogue: LDS quarter-transpose -> ROW-MAJOR Opart[sp][m][d] (R8).
//  5) fused merge: last split-block of each y-group (atomic+fence protocol
//     validated R6) merges via fully-coalesced float4 streams (row-major
//     layout kills R6's serial-scalar tail).
// Eliminates 2 of 3 kernel launches + their gaps (~40us of R10's 65us
// non-fa_main time).
// ---------------------------------------------------------------------------
__launch_bounds__(256, 2)
__global__ void fa_all(const float* __restrict__ Qp, const float* __restrict__ K,
                       const float* __restrict__ V,
                       _Float16* __restrict__ K16s, _Float16* __restrict__ Vs,
                       float* __restrict__ Opart,
                       float* __restrict__ lpart, float* __restrict__ mpart,
                       int* __restrict__ counters, float* __restrict__ Out, int tiles) {
    __shared__ float smem_f[8448];         // 33,792B union: prep Kl|Vl / 2x16KB ring
    __shared__ int flag_s;
    const int tid  = threadIdx.x;
    const int lane = tid & 63;
    const int wv   = tid >> 6;
    const int l31  = lane & 31;
    const int q5   = lane >> 5;
    const int sp   = blockIdx.x;           // split id (XCD = (sp + S*y)%8 = sp at S=8)
    const int m0   = blockIdx.y * 128 + wv * 32;
    const int nb   = gridDim.x * gridDim.y;
    const int lid  = blockIdx.y * gridDim.x + blockIdx.x;
    const float LOG2E = 1.44269504088896f;
    int* prep_ctr = counters + 64;

    // ---- phase 1: prep (fp32 -> f16 mfma-operand-order) ----
    {
        float* Kl = smem_f;                // 32 x 132
        float* Vl = smem_f + 4224;
        for (int tl = lid; tl < N_SEQ / 32; tl += nb) {
            const int n0 = tl * 32;
            #pragma unroll
            for (int kk = 0; kk < 4; kk++) {
                int idx = tid + 256 * kk;
                int nl = idx >> 5, c4 = idx & 31;
                float4 f = *(((const float4*)(K + (size_t)(n0 + nl) * HDIM)) + c4);
                float* dk = &Kl[nl * 132 + c4 * 4];
                dk[0] = f.x; dk[1] = f.y; dk[2] = f.z; dk[3] = f.w;
                float4 g = *(((const float4*)(V + (size_t)(n0 + nl) * HDIM)) + c4);
                float* dv = &Vl[nl * 132 + c4 * 4];
                dv[0] = g.x; dv[1] = g.y; dv[2] = g.z; dv[3] = g.w;
            }
            __syncthreads();
            #pragma unroll
            for (int rep = 0; rep < 2; rep++) {
                int ch = tid + rep * 256;
                int kc = ch >> 6, ln = ch & 63, r31 = ln & 31, rq5 = (ln >> 5) & 1;
                half8v h;
                #pragma unroll
                for (int j = 0; j < 8; j++) h[j] = (_Float16)Kl[r31 * 132 + kc * 16 + rq5 * 8 + j];
                *(half8v*)(K16s + (((size_t)tl * 8 + kc) * 64 + ln) * 8) = h;
            }
            #pragma unroll
            for (int rep = 0; rep < 2; rep++) {
                int ch = tid + rep * 256;
                int dt = ch >> 7, kc2 = (ch >> 6) & 1, ln = ch & 63, r31 = ln & 31, rq5 = (ln >> 5) & 1;
                half8v h;
                #pragma unroll
                for (int j = 0; j < 8; j++) h[j] = (_Float16)Vl[(kc2 * 16 + rq5 * 8 + j) * 132 + dt * 32 + r31];
                *(half8v*)(Vs + ((((size_t)tl * 4 + dt) * 2 + kc2) * 64 + ln) * 8) = h;
            }
            __syncthreads();               // LDS reuse / done
        }
    }

    // ---- Q fragments (overlaps other blocks' prep) ----
    half8v qf[8];
    {
        const float* qrow = Qp + (size_t)(m0 + l31) * HDIM;
        #pragma unroll
        for (int kc = 0; kc < 8; kc++) {
            const float4 a = *(const float4*)(qrow + kc * 16 + q5 * 8);
            const float4 b = *(const float4*)(qrow + kc * 16 + q5 * 8 + 4);
            half8v h;
            h[0] = (_Float16)(a.x * LOG2E); h[1] = (_Float16)(a.y * LOG2E);
            h[2] = (_Float16)(a.z * LOG2E); h[3] = (_Float16)(a.w * LOG2E);
            h[4] = (_Float16)(b.x * LOG2E); h[5] = (_Float16)(b.y * LOG2E);
            h[6] = (_Float16)(b.z * LOG2E); h[7] = (_Float16)(b.w * LOG2E);
            qf[kc] = h;
        }
    }

    // ---- phase 2: grid gate (all blocks resident by construction) ----
    if (tid == 0) {
        __threadfence();                   // release this block's K16s/Vs writes
        atomicAdd(prep_ctr, 1);
        while (atomicAdd(prep_ctr, 0) < nb) __builtin_amdgcn_s_sleep(8);
    }
    __syncthreads();
    __threadfence();                       // acquire all blocks' prep writes

    // ---- phase 3: main loop (R8 2-buffer pipeline) ----
    _Float16* ldsbuf0 = (_Float16*)smem_f;
    _Float16* ldsbuf1 = ldsbuf0 + 8192;

    floatx16 oacc[4];
    #pragma unroll
    for (int dt = 0; dt < 4; dt++)
        #pragma unroll
        for (int r = 0; r < 16; r++) oacc[dt][r] = 0.0f;

    float runm = -3.0e38f;
    float lsum = 0.0f;
    float palpha = 0.0f;
    bool  pflag = false;
    uint32 hpk[8];
    half8v va[8], vb[8];

    const size_t nt0 = (size_t)sp * tiles;

    stage_tile(K16s, Vs, ldsbuf0, nt0, wv, lane);
    __syncthreads();
    stage_tile(K16s, Vs, ldsbuf1, nt0 + 1, wv, lane);
    pipe_step<false>(qf, va, va, oacc, hpk, runm, lsum, palpha, pflag, ldsbuf0, lane, q5);
    __syncthreads();
    for (int p = 0; p < (tiles - 2) / 2; p++) {
        stage_tile(K16s, Vs, ldsbuf0, nt0 + 2 + 2 * p, wv, lane);
        pipe_step<true>(qf, vb, va, oacc, hpk, runm, lsum, palpha, pflag, ldsbuf1, lane, q5);
        __syncthreads();
        stage_tile(K16s, Vs, ldsbuf1, nt0 + 3 + 2 * p, wv, lane);
        pipe_step<true>(qf, va, vb, oacc, hpk, runm, lsum, palpha, pflag, ldsbuf0, lane, q5);
        __syncthreads();
    }
    pipe_step<true>(qf, vb, va, oacc, hpk, runm, lsum, palpha, pflag, ldsbuf1, lane, q5);
    if (pflag) {
        #pragma unroll
        for (int dt = 0; dt < 4; dt++)
            #pragma unroll
            for (int r = 0; r < 16; r++) oacc[dt][r] *= palpha;
    }
    do_pv(vb, hpk, oacc, q5);

    // ---- per-row (l, m) ----
    float ltot = lsum + __shfl_xor(lsum, 32, 64);
    if (lane < 32) {
        lpart[(size_t)sp * N_SEQ + m0 + l31] = ltot;
        mpart[(size_t)sp * N_SEQ + m0 + l31] = runm;
    }

    // ---- phase 4: LDS quarter-transpose -> row-major Opart[sp][m][d] ----
    float* ldsf = smem_f;                  // 32 rows x 132 pitch
    const size_t obase = ((size_t)sp * N_SEQ + blockIdx.y * 128) * HDIM;
    #pragma unroll
    for (int qtr = 0; qtr < 4; qtr++) {
        __syncthreads();
        if (wv == qtr) {
            #pragma unroll
            for (int dt = 0; dt < 4; dt++)
                #pragma unroll
                for (int g = 0; g < 4; g++) {
                    float4 v = make_float4(oacc[dt][4 * g + 0], oacc[dt][4 * g + 1],
                                           oacc[dt][4 * g + 2], oacc[dt][4 * g + 3]);
                    *(float4*)&ldsf[l31 * 132 + dt * 32 + g * 8 + q5 * 4] = v;
                }
        }
        __syncthreads();
        const int lrow = wv * 8 + (lane >> 3);
        const int c    = lane & 7;
        #pragma unroll
        for (int j = 0; j < 4; j++) {
            float4 v = *(const float4*)&ldsf[lrow * 132 + (j * 8 + c) * 4];
            *(float4*)&Opart[obase + (size_t)(qtr * 32 + lrow) * HDIM + (j * 8 + c) * 4] = v;
        }
    }

    // ---- phase 5: fused merge, last split-block of this y-group ----
    __syncthreads();                       // all Opart stores completed (vmcnt0@barrier)
    if (tid == 0) {
        __threadfence();                   // release our slice device-wide
        int old = atomicAdd(&counters[blockIdx.y], 1);
        flag_s = (old == (int)gridDim.x - 1);
    }
    __syncthreads();
    if (!flag_s) return;
    __threadfence();                       // acquire other splits' stores

    const int S   = gridDim.x;
    const int ym0 = blockIdx.y * 128;
    const int rg  = tid >> 4;              // 16 row-slots
    const int c   = tid & 15;              // 16 f4-slots (x2) per row
    for (int rr = 0; rr < 8; rr++) {
        const int m = ym0 + rr * 16 + rg;
        float mv[8], lv[8];
        #pragma unroll
        for (int s = 0; s < 8; s++)
            if (s < S) { mv[s] = mpart[(size_t)s * N_SEQ + m]; lv[s] = lpart[(size_t)s * N_SEQ + m]; }
        float M = -3.0e38f;
        #pragma unroll
        for (int s = 0; s < 8; s++) if (s < S) M = fmaxf(M, mv[s]);
        float wsc[8];
        float L = 0.0f;
        #pragma unroll
        for (int s = 0; s < 8; s++)
            if (s < S) { wsc[s] = __builtin_amdgcn_exp2f(mv[s] - M); L += lv[s] * wsc[s]; }
        const float inv = 1.0f / L;
        float4 a0 = make_float4(0.f, 0.f, 0.f, 0.f);
        float4 a1 = make_float4(0.f, 0.f, 0.f, 0.f);
        #pragma unroll
        for (int s = 0; s < 8; s++)
            if (s < S) {
                const float ww = wsc[s] * inv;
                const float* src = Opart + ((size_t)s * N_SEQ + m) * HDIM;
                float4 v = *(const float4*)&src[c * 4];
                a0.x += v.x * ww; a0.y += v.y * ww; a0.z += v.z * ww; a0.w += v.w * ww;
                v = *(const float4*)&src[(16 + c) * 4];
                a1.x += v.x * ww; a1.y += v.y * ww; a1.z += v.z * ww; a1.w += v.w * ww;
            }
        float* dst = Out + (size_t)m * HDIM;
        *(float4*)&dst[c * 4]        = a0;
        *(float4*)&dst[(16 + c) * 4] = a1;
    }
}

// ---------------------------------------------------------------------------
// Safety-net: naive fp32 flash attention (only if ws too small).
// ---------------------------------------------------------------------------
__global__ void fa_naive(const float* __restrict__ Q, const float* __restrict__ K,
                         const float* __restrict__ V, float* __restrict__ O) {
    const int m = blockIdx.x;
    const int t = threadIdx.x;
    __shared__ float qs[HDIM];
    __shared__ float ps[256];
    __shared__ float red[256];
    if (t < HDIM) qs[t] = Q[(size_t)m * HDIM + t] * 1.44269504f;
    __syncthreads();
    float om = -3.0e38f, ls = 0.0f, oa = 0.0f;
    for (int nb = 0; nb < N_SEQ; nb += 256) {
        const float* kr = K + (size_t)(nb + t) * HDIM;
        float s = 0.0f;
        #pragma unroll 8
        for (int d = 0; d < HDIM; d++) s += qs[d] * kr[d];
        red[t] = s; __syncthreads();
        for (int st = 128; st > 0; st >>= 1) { if (t < st) red[t] = fmaxf(red[t], red[t + st]); __syncthreads(); }
        float cm = red[0];
        __syncthreads();
        float mn = fmaxf(om, cm);
        float al = __builtin_amdgcn_exp2f(om - mn);
        om = mn;
        float pp = __builtin_amdgcn_exp2f(s - mn);
        ps[t] = pp; red[t] = pp; __syncthreads();
        for (int st = 128; st > 0; st >>= 1) { if (t < st) red[t] += red[t + st]; __syncthreads(); }
        float csum = red[0];
        ls = ls * al + csum;
        if (t < HDIM) {
            float acc = 0.0f;
            for (int j = 0; j < 256; j++) acc += ps[j] * V[(size_t)(nb + j) * HDIM + t];
            oa = oa * al + acc;
        }
        __syncthreads();
    }
    if (t < HDIM) O[(size_t)m * HDIM + t] = oa / ls;
}

// ---------------------------------------------------------------------------
extern "C" void kernel_launch(void* const* d_in, const int* in_sizes, int n_in,
                              void* d_out, int out_size, void* d_ws, size_t ws_size,
                              hipStream_t stream) {
    const float* q = (const float*)d_in[0];
    const float* k = (const float*)d_in[1];
    const float* v = (const float*)d_in[2];
    float* out = (float*)d_out;

    const size_t MB = 1024ull * 1024ull;
    int S = 0;
    for (int s = 8; s >= 1; s >>= 1) {
        size_t need = 4 * MB + (size_t)s * (4 * MB + 64 * 1024) + 4096;
        if (ws_size >= need) { S = s; break; }
    }
    if (S == 0) {
        fa_naive<<<N_SEQ, 256, 0, stream>>>(q, k, v, out);
        return;
    }
    char* ws = (char*)d_ws;
    _Float16* K16s = (_Float16*)ws;
    _Float16* Vs   = (_Float16*)(ws + 2 * MB);
    float* Opart   = (float*)(ws + 4 * MB);
    float* lpart   = (float*)(ws + 4 * MB + (size_t)S * 4 * MB);
    float* mpart   = lpart + (size_t)S * N_SEQ;
    int*   counters = (int*)(mpart + (size_t)S * N_SEQ);  // [64] merge + [1] prep gate

    hipMemsetAsync(counters, 0, 65 * sizeof(int), stream);
    fa_all<<<dim3(S, N_SEQ / 128), dim3(256), 0, stream>>>(
        q, k, v, K16s, Vs, Opart, lpart, mpart, counters, out, (N_SEQ / 32) / S);
}

// Round 12
// 119.528 us; speedup vs baseline: 1.9107x; 1.9107x over previous
//
#include <hip/hip_runtime.h>

#define N_SEQ 8192
#define HDIM  128

typedef _Float16 half8v  __attribute__((ext_vector_type(8)));
typedef float    floatx16 __attribute__((ext_vector_type(16)));
typedef unsigned int uint32;

// ---------------------------------------------------------------------------
// prep_kv: one block per 32-key tile. Stages K and V fp32 tiles in LDS, then
// writes f16 fragments in EXACT mfma operand order, lane-major, so fa_main's
// fragment loads are fully coalesced 1KB wave loads (and 1KB-chunk LDS-stageable).
// ---------------------------------------------------------------------------
__global__ void prep_kv(const float* __restrict__ K, const float* __restrict__ V,
                        _Float16* __restrict__ K16s, _Float16* __restrict__ Vs) {
    __shared__ float Kl[32 * 132];
    __shared__ float Vl[32 * 132];
    const int t  = threadIdx.x;
    const int nt = blockIdx.x;
    const int n0 = nt * 32;
    #pragma unroll
    for (int kk = 0; kk < 4; kk++) {
        int idx = t + 256 * kk;
        int nl = idx >> 5, c4 = idx & 31;
        float4 f = *(((const float4*)(K + (size_t)(n0 + nl) * HDIM)) + c4);
        float* dk = &Kl[nl * 132 + c4 * 4];
        dk[0] = f.x; dk[1] = f.y; dk[2] = f.z; dk[3] = f.w;
        float4 g = *(((const float4*)(V + (size_t)(n0 + nl) * HDIM)) + c4);
        float* dv = &Vl[nl * 132 + c4 * 4];
        dv[0] = g.x; dv[1] = g.y; dv[2] = g.z; dv[3] = g.w;
    }
    __syncthreads();
    #pragma unroll
    for (int rep = 0; rep < 2; rep++) {
        int ch = t + rep * 256;
        int kc = ch >> 6, lane = ch & 63, l31 = lane & 31, q5 = (lane >> 5) & 1;
        half8v h;
        #pragma unroll
        for (int j = 0; j < 8; j++) h[j] = (_Float16)Kl[l31 * 132 + kc * 16 + q5 * 8 + j];
        *(half8v*)(K16s + (((size_t)nt * 8 + kc) * 64 + lane) * 8) = h;
    }
    #pragma unroll
    for (int rep = 0; rep < 2; rep++) {
        int ch = t + rep * 256;
        int dt = ch >> 7, kc2 = (ch >> 6) & 1, lane = ch & 63, l31 = lane & 31, q5 = (lane >> 5) & 1;
        half8v h;
        #pragma unroll
        for (int j = 0; j < 8; j++) h[j] = (_Float16)Vl[(kc2 * 16 + q5 * 8 + j) * 132 + dt * 32 + l31];
        *(half8v*)(Vs + ((((size_t)nt * 4 + dt) * 2 + kc2) * 64 + lane) * 8) = h;
    }
}

// ---------------------------------------------------------------------------
// stage_tile: async global->LDS copy of one 32-key tile (K 8KB + V 8KB) into
// a 16KB LDS region, 4 chunks/wave. Layouts are lane-major 1KB chunks, so the
// wave-uniform-base + lane*16 LDS write pattern of global_load_lds matches.
// Completion fenced by the caller's __syncthreads (vmcnt(0) before s_barrier).
// ---------------------------------------------------------------------------
static __device__ __forceinline__ void stage_tile(
        const _Float16* __restrict__ K16s, const _Float16* __restrict__ Vs,
        _Float16* lds, size_t nt, int wv, int lane) {
    #pragma unroll
    for (int i = 0; i < 4; i++) {
        const int c = wv * 4 + i;
        const _Float16* base = (c < 8) ? (K16s + (nt * 8 + c) * 512)
                                       : (Vs + (nt * 8 + (size_t)(c - 8)) * 512);
        __builtin_amdgcn_global_load_lds(
            (const __attribute__((address_space(1))) void*)(base + lane * 8),
            (__attribute__((address_space(3))) void*)(lds + c * 512),
            16, 0, 0);
    }
}

// ---- PV: oacc += V(tile) . P(tile), P given as packed-f16 C-layout regs ----
static __device__ __forceinline__ void do_pv(const half8v (&vsrc)[8], const uint32 (&hpk)[8],
                                             floatx16 (&oacc)[4], int q5) {
    #pragma unroll
    for (int kc2 = 0; kc2 < 2; kc2++) {
        uint32 pass0 = q5 ? hpk[4 * kc2 + 0] : hpk[4 * kc2 + 2];
        uint32 pass1 = q5 ? hpk[4 * kc2 + 1] : hpk[4 * kc2 + 3];
        uint32 r0 = (uint32)__shfl_xor((int)pass0, 32, 64);
        uint32 r1 = (uint32)__shfl_xor((int)pass1, 32, 64);
        uint32 b0 = q5 ? r0 : hpk[4 * kc2 + 0];
        uint32 b1 = q5 ? r1 : hpk[4 * kc2 + 1];
        uint32 b2 = q5 ? hpk[4 * kc2 + 2] : r0;
        uint32 b3 = q5 ? hpk[4 * kc2 + 3] : r1;
        uint4 bu = make_uint4(b0, b1, b2, b3);
        half8v bfrag = __builtin_bit_cast(half8v, bu);
        #pragma unroll
        for (int dt = 0; dt < 4; dt++)
            oacc[dt] = __builtin_amdgcn_mfma_f32_32x32x16_f16(vsrc[dt * 2 + kc2], bfrag, oacc[dt], 0, 0, 0);
    }
}

// ---------------------------------------------------------------------------
// step64: one BN=64 phase (two 32-key sub-tiles A,B from one 32KB buffer).
// In-phase PV: V is ds_read AFTER softmax from the SAME buffer (stage writes
// go to the other buffer -> no cross-phase V registers, no race). Halves the
// number of barriers/phase-latency gaps vs the BN=32 pipeline (R8-R10 showed
// per-phase overhead ~3000cyc dominates; MFMA/exp work unchanged).
// Buffer layout: [K_A 8K][V_A 8K][K_B 8K][V_B 8K].
// ---------------------------------------------------------------------------
static __device__ __forceinline__ void step64(
        const half8v (&qf)[8], floatx16 (&oacc)[4],
        float& runm, float& lsum,
        const _Float16* lds, int lane, int q5) {
    // ---- S_A = K_A . Q^T ----
    half8v kf[8];
    #pragma unroll
    for (int kc = 0; kc < 8; kc++)
        kf[kc] = *(const half8v*)(lds + kc * 512 + lane * 8);
    floatx16 s0, s1;
    #pragma unroll
    for (int r = 0; r < 16; r++) { s0[r] = 0.0f; s1[r] = 0.0f; }
    #pragma unroll
    for (int kc = 0; kc < 4; kc++)
        s0 = __builtin_amdgcn_mfma_f32_32x32x16_f16(kf[kc], qf[kc], s0, 0, 0, 0);
    #pragma unroll
    for (int kc = 4; kc < 8; kc++)
        s1 = __builtin_amdgcn_mfma_f32_32x32x16_f16(kf[kc], qf[kc], s1, 0, 0, 0);
    float sA[16];
    #pragma unroll
    for (int r = 0; r < 16; r++) sA[r] = s0[r] + s1[r];
    // ---- S_B = K_B . Q^T (kf regs reused) ----
    #pragma unroll
    for (int kc = 0; kc < 8; kc++)
        kf[kc] = *(const half8v*)(lds + 8192 + kc * 512 + lane * 8);
    #pragma unroll
    for (int r = 0; r < 16; r++) { s0[r] = 0.0f; s1[r] = 0.0f; }
    #pragma unroll
    for (int kc = 0; kc < 4; kc++)
        s0 = __builtin_amdgcn_mfma_f32_32x32x16_f16(kf[kc], qf[kc], s0, 0, 0, 0);
    #pragma unroll
    for (int kc = 4; kc < 8; kc++)
        s1 = __builtin_amdgcn_mfma_f32_32x32x16_f16(kf[kc], qf[kc], s1, 0, 0, 0);
    float sB[16];
    #pragma unroll
    for (int r = 0; r < 16; r++) sB[r] = s0[r] + s1[r];
    // ---- softmax over 64 keys: max tree + cross-half shfl ----
    float tm[8];
    #pragma unroll
    for (int r = 0; r < 8; r++)
        tm[r] = fmaxf(fmaxf(sA[r], sA[r + 8]), fmaxf(sB[r], sB[r + 8]));
    #pragma unroll
    for (int w = 4; w; w >>= 1)
        #pragma unroll
        for (int r = 0; r < w; r++) tm[r] = fmaxf(tm[r], tm[r + w]);
    float cmax = fmaxf(tm[0], __shfl_xor(tm[0], 32, 64));
    // lazy rescale: only when max grew by >12 (p stays <= 2^12, f16-safe)
    if (__any(cmax > runm + 12.0f)) {
        const float mnew = fmaxf(runm, cmax);
        const float alpha = __builtin_amdgcn_exp2f(runm - mnew);
        #pragma unroll
        for (int dt = 0; dt < 4; dt++)
            #pragma unroll
            for (int r = 0; r < 16; r++) oacc[dt][r] *= alpha;
        lsum *= alpha;
        runm = mnew;
    }
    float pA[16], pB[16];
    #pragma unroll
    for (int r = 0; r < 16; r++) pA[r] = __builtin_amdgcn_exp2f(sA[r] - runm);
    #pragma unroll
    for (int r = 0; r < 16; r++) pB[r] = __builtin_amdgcn_exp2f(sB[r] - runm);
    float ts[8];
    #pragma unroll
    for (int r = 0; r < 8; r++) ts[r] = (pA[r] + pA[r + 8]) + (pB[r] + pB[r + 8]);
    #pragma unroll
    for (int w = 4; w; w >>= 1)
        #pragma unroll
        for (int r = 0; r < w; r++) ts[r] += ts[r + w];
    lsum += ts[0];
    uint32 hA[8], hB[8];
    #pragma unroll
    for (int t2 = 0; t2 < 8; t2++) {
        auto ka = __builtin_amdgcn_cvt_pkrtz(pA[2 * t2], pA[2 * t2 + 1]);
        hA[t2] = __builtin_bit_cast(uint32, ka);
        auto kb = __builtin_amdgcn_cvt_pkrtz(pB[2 * t2], pB[2 * t2 + 1]);
        hB[t2] = __builtin_bit_cast(uint32, kb);
    }
    // ---- PV: in-phase, V from same buffer (kf regs reused as V fragments) ----
    #pragma unroll
    for (int j = 0; j < 8; j++)
        kf[j] = *(const half8v*)(lds + (8 + j) * 512 + lane * 8);
    do_pv(kf, hA, oacc, q5);
    #pragma unroll
    for (int j = 0; j < 8; j++)
        kf[j] = *(const half8v*)(lds + 8192 + (8 + j) * 512 + lane * 8);
    do_pv(kf, hB, oacc, q5);
}

// ---------------------------------------------------------------------------
// Main flash kernel: BN=64 in-phase pipeline. 4 waves x 32 query rows,
// 64 keys/phase (two 32-key tiles per 32KB LDS buffer, double-buffered =
// 64KB/block -> 2 blocks/CU with 124-150 VGPR). 16 phases instead of 32:
// halves the per-phase serial overhead (barrier + load-latency gap + softmax
// chain) that R8-R10 profiling showed dominates (issue ~1100 of 4200
// cyc/phase; counted-vmcnt ring was neutral -> latency, not drain).
// In-phase PV removes the cross-phase V registers (va/vb, 64 VGPR) and the
// deferred-rescale flag machinery. Grid (S, N/128): XCD = sp at S=8.
// Grid-sync fusion attempts (R6, R11) both regressed badly -- 3 separate
// dispatches is the proven structure.
// ---------------------------------------------------------------------------
__launch_bounds__(256, 2)
__global__ void fa_main(const float* __restrict__ Qp, const _Float16* __restrict__ K16s,
                        const _Float16* __restrict__ Vs, float* __restrict__ Opart,
                        float* __restrict__ lpart, float* __restrict__ mpart, int tiles) {
    __shared__ _Float16 ldsbuf[2][16384];  // 2 x 32KB: [K_A|V_A|K_B|V_B]
    const int tid  = threadIdx.x;
    const int lane = tid & 63;
    const int wv   = tid >> 6;
    const int l31  = lane & 31;
    const int q5   = lane >> 5;
    const int sp   = blockIdx.x;           // split id (XCD = sp at S=8)
    const int m0   = blockIdx.y * 128 + wv * 32;
    const float LOG2E = 1.44269504088896f;

    half8v qf[8];
    {
        const float* qrow = Qp + (size_t)(m0 + l31) * HDIM;
        #pragma unroll
        for (int kc = 0; kc < 8; kc++) {
            const float4 a = *(const float4*)(qrow + kc * 16 + q5 * 8);
            const float4 b = *(const float4*)(qrow + kc * 16 + q5 * 8 + 4);
            half8v h;
            h[0] = (_Float16)(a.x * LOG2E); h[1] = (_Float16)(a.y * LOG2E);
            h[2] = (_Float16)(a.z * LOG2E); h[3] = (_Float16)(a.w * LOG2E);
            h[4] = (_Float16)(b.x * LOG2E); h[5] = (_Float16)(b.y * LOG2E);
            h[6] = (_Float16)(b.z * LOG2E); h[7] = (_Float16)(b.w * LOG2E);
            qf[kc] = h;
        }
    }

    floatx16 oacc[4];
    #pragma unroll
    for (int dt = 0; dt < 4; dt++)
        #pragma unroll
        for (int r = 0; r < 16; r++) oacc[dt][r] = 0.0f;

    float runm = -3.0e38f;
    float lsum = 0.0f;

    const size_t nt0 = (size_t)sp * tiles;
    const int phases = tiles >> 1;         // 64 keys per phase

    // prologue: stage phase 0 (tiles nt0, nt0+1) into buf0
    stage_tile(K16s, Vs, ldsbuf[0], nt0 + 0, wv, lane);
    stage_tile(K16s, Vs, ldsbuf[0] + 8192, nt0 + 1, wv, lane);
    __syncthreads();
    for (int ph = 0; ph < phases; ph++) {
        _Float16* cur = ldsbuf[ph & 1];
        _Float16* nxt = ldsbuf[(ph & 1) ^ 1];
        if (ph + 1 < phases) {
            stage_tile(K16s, Vs, nxt, nt0 + 2 * ph + 2, wv, lane);
            stage_tile(K16s, Vs, nxt + 8192, nt0 + 2 * ph + 3, wv, lane);
        }
        step64(qf, oacc, runm, lsum, cur, lane, q5);
        __syncthreads();                   // publishes nxt staging; cur reusable
    }

    // ---- per-row (l, m) ----
    float ltot = lsum + __shfl_xor(lsum, 32, 64);
    if (lane < 32) {
        lpart[(size_t)sp * N_SEQ + m0 + l31] = ltot;
        mpart[(size_t)sp * N_SEQ + m0 + l31] = runm;
    }

    // ---- epilogue: LDS quarter-transpose -> row-major Opart[sp][m][d] ----
    // oacc[dt][4g+e] holds column d = dt*32 + g*8 + q5*4 + e of row m0+l31.
    float* ldsf = (float*)ldsbuf;          // 32 rows x 132 pitch = 16.5KB
    const size_t obase = ((size_t)sp * N_SEQ + blockIdx.y * 128) * HDIM;
    #pragma unroll
    for (int qtr = 0; qtr < 4; qtr++) {
        __syncthreads();
        if (wv == qtr) {
            #pragma unroll
            for (int dt = 0; dt < 4; dt++)
                #pragma unroll
                for (int g = 0; g < 4; g++) {
                    float4 v = make_float4(oacc[dt][4 * g + 0], oacc[dt][4 * g + 1],
                                           oacc[dt][4 * g + 2], oacc[dt][4 * g + 3]);
                    *(float4*)&ldsf[l31 * 132 + dt * 32 + g * 8 + q5 * 4] = v;
                }
        }
        __syncthreads();
        const int lrow = wv * 8 + (lane >> 3);
        const int c    = lane & 7;
        #pragma unroll
        for (int j = 0; j < 4; j++) {
            float4 v = *(const float4*)&ldsf[lrow * 132 + (j * 8 + c) * 4];
            *(float4*)&Opart[obase + (size_t)(qtr * 32 + lrow) * HDIM + (j * 8 + c) * 4] = v;
        }
    }
}

// ---------------------------------------------------------------------------
// Merge: grid N/16 = 512 blocks x 256 threads (2 blocks/CU). Opart is
// row-major [s][m][d]: all loads/stores are coalesced float4 streams.
// ---------------------------------------------------------------------------
template <int S>
__global__ __launch_bounds__(256) void fa_merge(const float* __restrict__ Opart,
                                                const float* __restrict__ lpart,
                                                const float* __restrict__ mpart,
                                                float* __restrict__ Out) {
    const int t = threadIdx.x;
    const int m = blockIdx.x * 16 + (t >> 4);
    const int c = t & 15;

    float mv[S], lv[S];
    #pragma unroll
    for (int s = 0; s < S; s++) {
        mv[s] = mpart[(size_t)s * N_SEQ + m];
        lv[s] = lpart[(size_t)s * N_SEQ + m];
    }
    float M = -3.0e38f;
    #pragma unroll
    for (int s = 0; s < S; s++) M = fmaxf(M, mv[s]);
    float wsc[S];
    float L = 0.0f;
    #pragma unroll
    for (int s = 0; s < S; s++) {
        wsc[s] = __builtin_amdgcn_exp2f(mv[s] - M);
        L += lv[s] * wsc[s];
    }
    const float inv = 1.0f / L;

    float4 acc[2];
    #pragma unroll
    for (int j = 0; j < 2; j++) acc[j] = make_float4(0.f, 0.f, 0.f, 0.f);
    #pragma unroll
    for (int s = 0; s < S; s++) {
        const float ww = wsc[s] * inv;
        const float* src = Opart + ((size_t)s * N_SEQ + m) * HDIM;
        #pragma unroll
        for (int j = 0; j < 2; j++) {
            float4 v = *(const float4*)&src[(j * 16 + c) * 4];
            acc[j].x += v.x * ww; acc[j].y += v.y * ww;
            acc[j].z += v.z * ww; acc[j].w += v.w * ww;
        }
    }
    float* dst = Out + (size_t)m * HDIM;
    #pragma unroll
    for (int j = 0; j < 2; j++)
        *(float4*)&dst[(j * 16 + c) * 4] = acc[j];
}

// ---------------------------------------------------------------------------
// Safety-net: naive fp32 flash attention (only if ws too small).
// ---------------------------------------------------------------------------
__global__ void fa_naive(const float* __restrict__ Q, const float* __restrict__ K,
                         const float* __restrict__ V, float* __restrict__ O) {
    const int m = blockIdx.x;
    const int t = threadIdx.x;
    __shared__ float qs[HDIM];
    __shared__ float ps[256];
    __shared__ float red[256];
    if (t < HDIM) qs[t] = Q[(size_t)m * HDIM + t] * 1.44269504f;
    __syncthreads();
    float om = -3.0e38f, ls = 0.0f, oa = 0.0f;
    for (int nb = 0; nb < N_SEQ; nb += 256) {
        const float* kr = K + (size_t)(nb + t) * HDIM;
        float s = 0.0f;
        #pragma unroll 8
        for (int d = 0; d < HDIM; d++) s += qs[d] * kr[d];
        red[t] = s; __syncthreads();
        for (int st = 128; st > 0; st >>= 1) { if (t < st) red[t] = fmaxf(red[t], red[t + st]); __syncthreads(); }
        float cm = red[0];
        __syncthreads();
        float mn = fmaxf(om, cm);
        float al = __builtin_amdgcn_exp2f(om - mn);
        om = mn;
        float pp = __builtin_amdgcn_exp2f(s - mn);
        ps[t] = pp; red[t] = pp; __syncthreads();
        for (int st = 128; st > 0; st >>= 1) { if (t < st) red[t] += red[t + st]; __syncthreads(); }
        float csum = red[0];
        ls = ls * al + csum;
        if (t < HDIM) {
            float acc = 0.0f;
            for (int j = 0; j < 256; j++) acc += ps[j] * V[(size_t)(nb + j) * HDIM + t];
            oa = oa * al + acc;
        }
        __syncthreads();
    }
    if (t < HDIM) O[(size_t)m * HDIM + t] = oa / ls;
}

// ---------------------------------------------------------------------------
extern "C" void kernel_launch(void* const* d_in, const int* in_sizes, int n_in,
                              void* d_out, int out_size, void* d_ws, size_t ws_size,
                              hipStream_t stream) {
    const float* q = (const float*)d_in[0];
    const float* k = (const float*)d_in[1];
    const float* v = (const float*)d_in[2];
    float* out = (float*)d_out;

    const size_t MB = 1024ull * 1024ull;
    int S = 0;
    for (int s = 8; s >= 1; s >>= 1) {               // S=8: known-good config
        size_t need = 4 * MB + (size_t)s * (4 * MB + 64 * 1024);
        if (ws_size >= need) { S = s; break; }
    }
    if (S == 0) {
        fa_naive<<<N_SEQ, 256, 0, stream>>>(q, k, v, out);
        return;
    }
    char* ws = (char*)d_ws;
    _Float16* K16s = (_Float16*)ws;
    _Float16* Vs   = (_Float16*)(ws + 2 * MB);
    float* Opart   = (float*)(ws + 4 * MB);
    float* lpart   = (float*)(ws + 4 * MB + (size_t)S * 4 * MB);
    float* mpart   = lpart + (size_t)S * N_SEQ;

    prep_kv<<<dim3(N_SEQ / 32), dim3(256), 0, stream>>>(k, v, K16s, Vs);
    fa_main<<<dim3(S, N_SEQ / 128), dim3(256), 0, stream>>>(q, K16s, Vs, Opart, lpart, mpart, (N_SEQ / 32) / S);
    dim3 mg(N_SEQ / 16);
    switch (S) {
        case 8:  fa_merge<8> <<<mg, dim3(256), 0, stream>>>(Opart, lpart, mpart, out); break;
        case 4:  fa_merge<4> <<<mg, dim3(256), 0, stream>>>(Opart, lpart, mpart, out); break;
        case 2:  fa_merge<2> <<<mg, dim3(256), 0, stream>>>(Opart, lpart, mpart, out); break;
        default: fa_merge<1> <<<mg, dim3(256), 0, stream>>>(Opart, lpart, mpart, out); break;
    }
}